// Round 11
// baseline (480.246 us; speedup 1.0000x reference)
//
#include <hip/hip_runtime.h>

// B=16, NQ=NK=784, D_MODEL=512, H=8, DK=DV=64
#define SZX ((size_t)12544 * 512)   // elements of one [B*784, 512] matrix
#define WSEG ((size_t)262144)       // one 512x512 weight

typedef __attribute__((ext_vector_type(8))) short short8;
typedef __attribute__((ext_vector_type(4))) short short4s;
typedef __attribute__((ext_vector_type(4))) float floatx4;

typedef const __attribute__((address_space(1))) void* gas_cvp;
typedef __attribute__((address_space(3))) void* las_vp;

__device__ __forceinline__ void gl_lds16(const void* g, void* l) {
    __builtin_amdgcn_global_load_lds((gas_cvp)g, (las_vp)l, 16, 0, 0);
}

__device__ __forceinline__ unsigned short f2bf(float f) {
    unsigned int u = __float_as_uint(f);
    u += 0x7fffu + ((u >> 16) & 1u);   // RNE
    return (unsigned short)(u >> 16);
}

__device__ __forceinline__ short8 cvt8(floatx4 a, floatx4 b) {
    short8 r;
    r[0] = (short)f2bf(a[0]); r[1] = (short)f2bf(a[1]);
    r[2] = (short)f2bf(a[2]); r[3] = (short)f2bf(a[3]);
    r[4] = (short)f2bf(b[0]); r[5] = (short)f2bf(b[1]);
    r[6] = (short)f2bf(b[2]); r[7] = (short)f2bf(b[3]);
    return r;
}

__device__ __forceinline__ short8 lds_read8(const unsigned short* p) {
    // p is 8B-aligned (not 16B) — two b64 reads
    short4s a = *(const short4s*)p;
    short4s b = *(const short4s*)(p + 4);
    return __builtin_shufflevector(a, b, 0, 1, 2, 3, 4, 5, 6, 7);
}

#define MFMA16(a, b, c) __builtin_amdgcn_mfma_f32_16x16x32_bf16(a, b, c, 0, 0, 0)

// ---------------- weight transpose + convert: Wt[o][i] = bf16(W[i][o]) ------------
__global__ void transpose_cvt(const float* __restrict__ W0, const float* __restrict__ W1,
                              const float* __restrict__ W2, const float* __restrict__ W3,
                              unsigned short* __restrict__ out) {
    __shared__ float tile[32][33];
    const float* W = blockIdx.z == 0 ? W0 : blockIdx.z == 1 ? W1 : blockIdx.z == 2 ? W2 : W3;
    unsigned short* O = out + (size_t)blockIdx.z * WSEG;
    int x = blockIdx.x * 32 + threadIdx.x;
    int y0 = blockIdx.y * 32;
    for (int k = threadIdx.y; k < 32; k += 8)
        tile[k][threadIdx.x] = W[(size_t)(y0 + k) * 512 + x];
    __syncthreads();
    int xo = blockIdx.y * 32 + threadIdx.x;
    int yo0 = blockIdx.x * 32;
    for (int k = threadIdx.y; k < 32; k += 8)
        O[(size_t)(yo0 + k) * 512 + xo] = f2bf(tile[threadIdx.x][k]);
}

// ---------------- merged QKV projection GEMM, v8 (UNCHANGED — validated R8) -------
__global__ __launch_bounds__(256) void gemm_qkv(
    const float* __restrict__ Xq, const float* __restrict__ Xk,
    const float* __restrict__ Xv, const unsigned short* __restrict__ Wt,
    const float* __restrict__ bq, const float* __restrict__ bk, const float* __restrict__ bv,
    unsigned short* __restrict__ Qb, unsigned short* __restrict__ Kb,
    unsigned short* __restrict__ Vtb)
{
    __shared__ float Xls[128 * 64];            // 32KB f32 X-tile (granule-swizzled)
    __shared__ unsigned short Wls[128 * 64];   // 16KB bf16 W-tile (granule-swizzled)
    int z = blockIdx.z;
    const float* X = z == 0 ? Xq : z == 1 ? Xk : Xv;
    const unsigned short* Wz = Wt + (size_t)z * WSEG;
    const float* bias = z == 0 ? bq : z == 1 ? bk : bv;

    int tid = threadIdx.x;
    int lane = tid & 63, wave = tid >> 6;
    int wm = wave & 1, wn = wave >> 1;
    int c16 = lane & 15, g = lane >> 4;

    int G = blockIdx.x;
    int i98, i4;
    if (G < 384) { i98 = (G >> 5) * 8 + (G & 7); i4 = (G >> 3) & 3; }
    else         { int r = G - 384; i98 = 96 + (r & 1); i4 = r >> 1; }

    const float* Xbase = X + (size_t)i98 * 128 * 512;
    const unsigned short* Wbase = Wz + (size_t)i4 * 128 * 512;
    int tm = (z < 2) ? i98 : i4;
    int tn = (z < 2) ? i4 : i98;
    int wx = (z < 2) ? wm : wn;
    int ww = (z < 2) ? wn : wm;

    floatx4 acc[4][4];
#pragma unroll
    for (int i = 0; i < 4; i++)
#pragma unroll
        for (int j = 0; j < 4; j++) acc[i][j] = (floatx4){0.f, 0.f, 0.f, 0.f};

    for (int kb = 0; kb < 8; ++kb) {
        int k0 = kb * 64;
#pragma unroll
        for (int rep = 0; rep < 8; ++rep) {
            int slot = rep * 256 + tid;
            int row = slot >> 4, gc = slot & 15;
            int src = (gc & 8) | ((gc & 7) ^ (row & 7));
            gl_lds16(Xbase + (size_t)row * 512 + k0 + src * 4, &Xls[slot * 4]);
        }
#pragma unroll
        for (int rep = 0; rep < 4; ++rep) {
            int slot = rep * 256 + tid;
            int row = slot >> 3, gc = slot & 7;
            int src = gc ^ (row & 7);
            gl_lds16(Wbase + (size_t)row * 512 + k0 + src * 8, &Wls[slot * 8]);
        }
        __syncthreads();

#pragma unroll
        for (int kk = 0; kk < 2; ++kk) {
            short8 xf[4], wf[4];
#pragma unroll
            for (int i = 0; i < 4; i++) {
                int row = wx * 64 + i * 16 + c16;
                int sw = row & 7;
                int g0 = kk * 8 + 2 * g;
                int p0 = (g0 & 8) | ((g0 & 7) ^ sw);
                int p1 = ((g0 + 1) & 8) | (((g0 + 1) & 7) ^ sw);
                floatx4 a  = *(const floatx4*)&Xls[row * 64 + p0 * 4];
                floatx4 b2 = *(const floatx4*)&Xls[row * 64 + p1 * 4];
                xf[i] = cvt8(a, b2);
            }
#pragma unroll
            for (int j = 0; j < 4; j++) {
                int row = ww * 64 + j * 16 + c16;
                int gl = kk * 4 + g;
                wf[j] = *(const short8*)&Wls[row * 64 + (gl ^ (row & 7)) * 8];
            }
            if (z < 2) {
#pragma unroll
                for (int i = 0; i < 4; i++)
#pragma unroll
                    for (int j = 0; j < 4; j++)
                        acc[i][j] = MFMA16(xf[i], wf[j], acc[i][j]);
            } else {
#pragma unroll
                for (int i = 0; i < 4; i++)
#pragma unroll
                    for (int j = 0; j < 4; j++)
                        acc[i][j] = MFMA16(wf[i], xf[j], acc[i][j]);
            }
        }
        __syncthreads();
    }

#pragma unroll
    for (int j = 0; j < 4; j++) {
        int n = tn * 128 + wn * 64 + j * 16 + c16;
        int bi = n / 784, nn = n - bi * 784;         // z==2 only
        float bvn = (z < 2) ? bias[n] : 0.f;
#pragma unroll
        for (int i = 0; i < 4; i++) {
#pragma unroll
            for (int r4 = 0; r4 < 4; r4++) {
                int m = tm * 128 + wm * 64 + i * 16 + g * 4 + r4;
                float v = acc[i][j][r4] + ((z < 2) ? bvn : bias[m]);
                if (z == 0)      Qb[(size_t)m * 512 + n] = f2bf(v);
                else if (z == 1) Kb[(size_t)m * 512 + n] = f2bf(v);
                else {
                    int h = m >> 6, d = m & 63;
                    Vtb[(((size_t)bi * 8 + h) * 64 + d) * 784 + nn] = f2bf(v);
                }
            }
        }
    }
}

// ---------------- output projection, v9 (UNCHANGED — validated R9) ----------------
__global__ __launch_bounds__(256) void gemm_out(
    const unsigned short* __restrict__ Wto, const unsigned short* __restrict__ ctx,
    const float* __restrict__ bo, float* __restrict__ out)
{
    __shared__ unsigned short Als[128 * 64];   // 16KB Wto tile (granule-swizzled)
    __shared__ unsigned short Bls[128 * 64];   // 16KB ctx tile (granule-swizzled)
    int tid = threadIdx.x;
    int lane = tid & 63, wave = tid >> 6;
    int wm = wave & 1, wn = wave >> 1;
    int c16 = lane & 15, g = lane >> 4;

    int G = blockIdx.x;
    int i98, i4;
    if (G < 384) { i98 = (G >> 5) * 8 + (G & 7); i4 = (G >> 3) & 3; }
    else         { int r = G - 384; i98 = 96 + (r & 1); i4 = r >> 1; }
    int tm = i4, tn = i98;

    const unsigned short* Abase = Wto + (size_t)tm * 128 * 512;
    const unsigned short* Bbase = ctx + (size_t)tn * 128 * 512;

    floatx4 acc[4][4];
#pragma unroll
    for (int i = 0; i < 4; i++)
#pragma unroll
        for (int j = 0; j < 4; j++) acc[i][j] = (floatx4){0.f, 0.f, 0.f, 0.f};

    for (int kb = 0; kb < 8; ++kb) {
        int k0 = kb * 64;
#pragma unroll
        for (int rep = 0; rep < 4; ++rep) {
            int slot = rep * 256 + tid;
            int row = slot >> 3, gc = slot & 7;
            int src = gc ^ (row & 7);
            gl_lds16(Abase + (size_t)row * 512 + k0 + src * 8, &Als[slot * 8]);
            gl_lds16(Bbase + (size_t)row * 512 + k0 + src * 8, &Bls[slot * 8]);
        }
        __syncthreads();

#pragma unroll
        for (int kk = 0; kk < 2; ++kk) {
            short8 af[4], bfr[4];
#pragma unroll
            for (int i = 0; i < 4; i++) {
                int row = wm * 64 + i * 16 + c16;
                int gl = kk * 4 + g;
                af[i] = *(const short8*)&Als[row * 64 + (gl ^ (row & 7)) * 8];
            }
#pragma unroll
            for (int j = 0; j < 4; j++) {
                int row = wn * 64 + j * 16 + c16;
                int gl = kk * 4 + g;
                bfr[j] = *(const short8*)&Bls[row * 64 + (gl ^ (row & 7)) * 8];
            }
#pragma unroll
            for (int i = 0; i < 4; i++)
#pragma unroll
                for (int j = 0; j < 4; j++)
                    acc[i][j] = MFMA16(af[i], bfr[j], acc[i][j]);
        }
        __syncthreads();
    }

#pragma unroll
    for (int j = 0; j < 4; j++) {
        int n = tn * 128 + wn * 64 + j * 16 + c16;
        int bi = n / 784, q = n - bi * 784;
#pragma unroll
        for (int i = 0; i < 4; i++) {
#pragma unroll
            for (int r4 = 0; r4 < 4; r4++) {
                int m = tm * 128 + wm * 64 + i * 16 + g * 4 + r4;
                out[((size_t)bi * 512 + m) * 784 + q] = acc[i][j][r4] + bo[m];
            }
        }
    }
}

// ---------------- fused attention v11: v0 structure, k-tile loop unrolled x2 ------
// R10's K-split regressed (FETCH +28MB: Q duplication + L2 locality loss). This
// keeps v0's traffic EXACTLY (same addresses, same counts — FETCH ~59MB is the
// tripwire) and applies the mechanism that won R8/R9: halve the number of
// serialization points and widen the independent-load window. Two k-tiles per
// loop body, phases explicitly separated (QK_A,QK_B | SM_A,SM_B | PV_A,PV_B):
// the scheduler sees 64 corr gathers (the cold ~900cy stream) + 2 K-tile load
// sets in one straight-line block -> 2x memory-level parallelism on the
// latency-critical path. Plds parity: tile A -> 0, tile B -> 1. 13 = 6x2 + 1
// tail. +32 VGPR for the second s[][] (grid-limited at 3.1 blocks/CU, so VGPR
// up to ~170 costs nothing). No setprio, no launch_bounds min-arg (R2), no DMA.
// Spill tripwire: WRITE_SIZE must stay 12544.
__global__ __launch_bounds__(256) void attn_kernel(
    const unsigned short* __restrict__ Qb,
    const unsigned short* __restrict__ Kb,
    const unsigned short* __restrict__ Vtb,
    const float* __restrict__ corr,
    unsigned short* __restrict__ ctx)
{
    __shared__ unsigned short Plds[2][4][2][16][68];   // [parity][wave][u][row][key+pad]
    int b = blockIdx.x, qt = blockIdx.y, hh = blockIdx.z;
    int tid = threadIdx.x;
    int lane = tid & 63, w = tid >> 6;
    int h = hh * 4 + w;
    int c16 = lane & 15, g = lane >> 4;
    int q0 = qt * 32;

    short8 aq[2][2];
#pragma unroll
    for (int u = 0; u < 2; ++u) {
        int row = q0 + u * 16 + c16; row = row < 784 ? row : 783;
        const unsigned short* qp = Qb + (size_t)(b * 784 + row) * 512 + h * 64 + g * 8;
        aq[u][0] = *(const short8*)qp;
        aq[u][1] = *(const short8*)(qp + 32);
    }

    floatx4 o[2][4];
    float l[2][4];
#pragma unroll
    for (int u = 0; u < 2; ++u)
#pragma unroll
        for (int nt = 0; nt < 4; nt++) { o[u][nt] = (floatx4){0.f, 0.f, 0.f, 0.f}; l[u][nt] = 0.f; }

    const float* corrb = corr + (size_t)b * 784 * 784;
    int crow[2][4];
#pragma unroll
    for (int u = 0; u < 2; ++u)
#pragma unroll
        for (int r = 0; r < 4; ++r) {
            int rr = q0 + u * 16 + g * 4 + r; rr = rr < 784 ? rr : 783;
            crow[u][r] = rr * 784;
        }

    const unsigned short* Vh = Vtb + ((size_t)(b * 8 + h)) * 64 * 784;
    const unsigned short* Kh = Kb + (size_t)b * 784 * 512 + h * 64;

    // ---- phase helpers (inlined; `par` folds to a constant at each call site) ----
    auto QK = [&](int it, floatx4 (&s)[2][4]) {
        int k0 = it * 64;
#pragma unroll
        for (int t = 0; t < 4; ++t) {
            int key = k0 + t * 16 + c16; key = key < 784 ? key : 783;
            const unsigned short* kp = Kh + (size_t)key * 512 + g * 8;
            short8 k0f = *(const short8*)kp;
            short8 k1f = *(const short8*)(kp + 32);
#pragma unroll
            for (int u = 0; u < 2; ++u) {
                floatx4 zz = (floatx4){0.f, 0.f, 0.f, 0.f};
                zz = MFMA16(aq[u][0], k0f, zz);
                zz = MFMA16(aq[u][1], k1f, zz);
                s[u][t] = zz;
            }
        }
    };
    auto SM = [&](int it, int par, floatx4 (&s)[2][4]) {
        int k0 = it * 64;
        unsigned short* pbase = &Plds[par][w][0][0][0];
#pragma unroll
        for (int u = 0; u < 2; ++u)
#pragma unroll
            for (int t = 0; t < 4; ++t) {
                int key = k0 + t * 16 + c16;
                bool valid = key < 784;
                int kc = valid ? key : 783;
#pragma unroll
                for (int r = 0; r < 4; ++r) {
                    float cv = corrb[crow[u][r] + kc];
                    float sv = fmaf(s[u][t][r], 0.125f, cv);
                    float pv = valid ? __expf(sv) : 0.f;
                    l[u][r] += pv;
                    pbase[(u * 16 + g * 4 + r) * 68 + t * 16 + c16] = f2bf(pv);
                }
            }
    };
    auto PV = [&](int it, int par) {
        int k0 = it * 64;
#pragma unroll
        for (int u = 0; u < 2; ++u) {
            const unsigned short* pr = &Plds[par][w][u][c16][0];
            short8 pa0 = lds_read8(pr + g * 8);
            short8 pa1 = lds_read8(pr + 32 + g * 8);
#pragma unroll
            for (int nt = 0; nt < 4; ++nt) {
                int d = nt * 16 + c16;
                const unsigned short* vp = Vh + (size_t)d * 784 + k0 + g * 8;
                short8 v0 = *(const short8*)vp;
                short8 v1 = *(const short8*)(vp + 32);
                o[u][nt] = MFMA16(pa0, v0, o[u][nt]);
                o[u][nt] = MFMA16(pa1, v1, o[u][nt]);
            }
        }
    };

    // 6 double-iterations + 1 tail; phases batched pairwise for 2x load MLP
    for (int ip = 0; ip < 6; ++ip) {
        int itA = ip * 2, itB = itA + 1;
        floatx4 sA[2][4], sB[2][4];
        QK(itA, sA);
        QK(itB, sB);
        SM(itA, 0, sA);
        SM(itB, 1, sB);
        PV(itA, 0);
        PV(itB, 1);
    }
    {   // tail it = 12
        floatx4 sA[2][4];
        QK(12, sA);
        SM(12, 0, sA);
        PV(12, 0);
    }

    // normalize and store
#pragma unroll
    for (int u = 0; u < 2; ++u)
#pragma unroll
        for (int r = 0; r < 4; ++r) {
            float lv = l[u][r];
            lv += __shfl_xor(lv, 1);
            lv += __shfl_xor(lv, 2);
            lv += __shfl_xor(lv, 4);
            lv += __shfl_xor(lv, 8);
            l[u][r] = 1.0f / lv;
        }
#pragma unroll
    for (int u = 0; u < 2; ++u)
#pragma unroll
        for (int r = 0; r < 4; ++r) {
            int row = q0 + u * 16 + g * 4 + r;
            if (row < 784) {
#pragma unroll
                for (int nt = 0; nt < 4; ++nt)
                    ctx[(size_t)(b * 784 + row) * 512 + h * 64 + nt * 16 + c16] =
                        f2bf(o[u][nt][r] * l[u][r]);
            }
        }
}

extern "C" void kernel_launch(void* const* d_in, const int* in_sizes, int n_in,
                              void* d_out, int out_size, void* d_ws, size_t ws_size,
                              hipStream_t stream) {
    (void)in_sizes; (void)n_in; (void)out_size; (void)ws_size;
    const float* queries = (const float*)d_in[0];
    const float* keys    = (const float*)d_in[1];
    const float* values  = (const float*)d_in[2];
    const float* corr    = (const float*)d_in[3];
    const float* Wq = (const float*)d_in[4];
    const float* bq = (const float*)d_in[5];
    const float* Wk = (const float*)d_in[6];
    const float* bk = (const float*)d_in[7];
    const float* Wv = (const float*)d_in[8];
    const float* bv = (const float*)d_in[9];
    const float* Wo = (const float*)d_in[10];
    const float* bo = (const float*)d_in[11];

    // workspace: Qb, Kb, Vtb, ctx (bf16, SZX each) + Wt (4 x WSEG bf16) = 53.5 MB
    unsigned short* Qb  = (unsigned short*)d_ws;
    unsigned short* Kb  = Qb + SZX;
    unsigned short* Vtb = Kb + SZX;
    unsigned short* ctx = Vtb + SZX;
    unsigned short* Wt  = ctx + SZX;

    transpose_cvt<<<dim3(16, 16, 4), dim3(32, 8), 0, stream>>>(Wq, Wk, Wv, Wo, Wt);
    gemm_qkv<<<dim3(392, 1, 3), 256, 0, stream>>>(queries, keys, values, Wt,
                                                  bq, bk, bv, Qb, Kb, Vtb);
    attn_kernel<<<dim3(16, 25, 2), 256, 0, stream>>>(Qb, Kb, Vtb, corr, ctx);
    gemm_out<<<dim3(392), 256, 0, stream>>>(Wt + 3 * WSEG, ctx, bo, (float*)d_out);
}

// Round 12
// 317.138 us; speedup vs baseline: 1.5143x; 1.5143x over previous
//
#include <hip/hip_runtime.h>

// B=16, NQ=NK=784, D_MODEL=512, H=8, DK=DV=64
#define SZX ((size_t)12544 * 512)   // elements of one [B*784, 512] matrix
#define WSEG ((size_t)262144)       // one 512x512 weight

typedef __attribute__((ext_vector_type(8))) short short8;
typedef __attribute__((ext_vector_type(4))) short short4s;
typedef __attribute__((ext_vector_type(4))) float floatx4;

typedef const __attribute__((address_space(1))) void* gas_cvp;
typedef __attribute__((address_space(3))) void* las_vp;

__device__ __forceinline__ void gl_lds16(const void* g, void* l) {
    __builtin_amdgcn_global_load_lds((gas_cvp)g, (las_vp)l, 16, 0, 0);
}

__device__ __forceinline__ unsigned short f2bf(float f) {
    unsigned int u = __float_as_uint(f);
    u += 0x7fffu + ((u >> 16) & 1u);   // RNE
    return (unsigned short)(u >> 16);
}

__device__ __forceinline__ short8 cvt8(floatx4 a, floatx4 b) {
    short8 r;
    r[0] = (short)f2bf(a[0]); r[1] = (short)f2bf(a[1]);
    r[2] = (short)f2bf(a[2]); r[3] = (short)f2bf(a[3]);
    r[4] = (short)f2bf(b[0]); r[5] = (short)f2bf(b[1]);
    r[6] = (short)f2bf(b[2]); r[7] = (short)f2bf(b[3]);
    return r;
}

__device__ __forceinline__ short8 lds_read8(const unsigned short* p) {
    // p is 8B-aligned (not 16B) — two b64 reads
    short4s a = *(const short4s*)p;
    short4s b = *(const short4s*)(p + 4);
    return __builtin_shufflevector(a, b, 0, 1, 2, 3, 4, 5, 6, 7);
}

#define MFMA16(a, b, c) __builtin_amdgcn_mfma_f32_16x16x32_bf16(a, b, c, 0, 0, 0)

// ---------------- weight transpose + convert: Wt[o][i] = bf16(W[i][o]) ------------
__global__ void transpose_cvt(const float* __restrict__ W0, const float* __restrict__ W1,
                              const float* __restrict__ W2, const float* __restrict__ W3,
                              unsigned short* __restrict__ out) {
    __shared__ float tile[32][33];
    const float* W = blockIdx.z == 0 ? W0 : blockIdx.z == 1 ? W1 : blockIdx.z == 2 ? W2 : W3;
    unsigned short* O = out + (size_t)blockIdx.z * WSEG;
    int x = blockIdx.x * 32 + threadIdx.x;
    int y0 = blockIdx.y * 32;
    for (int k = threadIdx.y; k < 32; k += 8)
        tile[k][threadIdx.x] = W[(size_t)(y0 + k) * 512 + x];
    __syncthreads();
    int xo = blockIdx.y * 32 + threadIdx.x;
    int yo0 = blockIdx.x * 32;
    for (int k = threadIdx.y; k < 32; k += 8)
        O[(size_t)(yo0 + k) * 512 + xo] = f2bf(tile[threadIdx.x][k]);
}

// ---------------- merged QKV projection GEMM, v12 ---------------------------------
// v8 (validated R8) with ONE change: X is reg-staged as bf16 (global f32 -> reg
// -> cvt8 -> swizzled ds_write_b128) instead of f32 gl_lds. Same f2bf on the
// same values in the same MFMA order -> bit-identical. Mechanism: LDS 48->32KB
// per block -> 3->5 blocks/CU -> capacity 1280 >= 1176 blocks (was 768: ~1.5
// dispatch generations of tail). Fragment reads for X become identical to W
// (no per-read cvt). Reg-staging also legitimately enables the direct swizzled
// LDS write (per-lane scatter, which gl_lds cannot do — rule #21 satisfied by
// write-side swizzle + read-side swizzle). W path unchanged (gl_lds + inverse-
// swizzled source). __syncthreads drains both vmcnt (W DMA) and lgkmcnt (X
// ds_writes) as before.
__global__ __launch_bounds__(256) void gemm_qkv(
    const float* __restrict__ Xq, const float* __restrict__ Xk,
    const float* __restrict__ Xv, const unsigned short* __restrict__ Wt,
    const float* __restrict__ bq, const float* __restrict__ bk, const float* __restrict__ bv,
    unsigned short* __restrict__ Qb, unsigned short* __restrict__ Kb,
    unsigned short* __restrict__ Vtb)
{
    __shared__ unsigned short Xls[128 * 64];   // 16KB bf16 X-tile (granule-swizzled)
    __shared__ unsigned short Wls[128 * 64];   // 16KB bf16 W-tile (granule-swizzled)
    int z = blockIdx.z;
    const float* X = z == 0 ? Xq : z == 1 ? Xk : Xv;
    const unsigned short* Wz = Wt + (size_t)z * WSEG;
    const float* bias = z == 0 ? bq : z == 1 ? bk : bv;

    int tid = threadIdx.x;
    int lane = tid & 63, wave = tid >> 6;
    int wm = wave & 1, wn = wave >> 1;
    int c16 = lane & 15, g = lane >> 4;

    // XCD-sibling remap: blocks sharing an X row-tile get ids congruent mod 8.
    int G = blockIdx.x;
    int i98, i4;
    if (G < 384) { i98 = (G >> 5) * 8 + (G & 7); i4 = (G >> 3) & 3; }
    else         { int r = G - 384; i98 = 96 + (r & 1); i4 = r >> 1; }

    const float* Xbase = X + (size_t)i98 * 128 * 512;
    const unsigned short* Wbase = Wz + (size_t)i4 * 128 * 512;
    int tm = (z < 2) ? i98 : i4;
    int tn = (z < 2) ? i4 : i98;
    int wx = (z < 2) ? wm : wn;
    int ww = (z < 2) ? wn : wm;

    floatx4 acc[4][4];
#pragma unroll
    for (int i = 0; i < 4; i++)
#pragma unroll
        for (int j = 0; j < 4; j++) acc[i][j] = (floatx4){0.f, 0.f, 0.f, 0.f};

    for (int kb = 0; kb < 8; ++kb) {
        int k0 = kb * 64;
        // stage W bf16 via gl_lds (unchanged): 4 passes; src granule = gc^(row&7)
#pragma unroll
        for (int rep = 0; rep < 4; ++rep) {
            int slot = rep * 256 + tid;
            int row = slot >> 3, gc = slot & 7;
            int src = gc ^ (row & 7);
            gl_lds16(Wbase + (size_t)row * 512 + k0 + src * 8, &Wls[slot * 8]);
        }
        // reg-stage X: 128 rows x 8 granules(16B bf16 = 8 elems); 4 granules/thread.
        // Load 8 f32 (2 float4), convert, ds_write_b128 at swizzled position.
#pragma unroll
        for (int rep = 0; rep < 4; ++rep) {
            int slot = rep * 256 + tid;
            int row = slot >> 3, gc = slot & 7;
            const float* src = Xbase + (size_t)row * 512 + k0 + gc * 8;
            floatx4 a  = *(const floatx4*)src;
            floatx4 b2 = *(const floatx4*)(src + 4);
            *(short8*)&Xls[row * 64 + (gc ^ (row & 7)) * 8] = cvt8(a, b2);
        }
        __syncthreads();

#pragma unroll
        for (int kk = 0; kk < 2; ++kk) {
            short8 xf[4], wf[4];
#pragma unroll
            for (int i = 0; i < 4; i++) {
                int row = wx * 64 + i * 16 + c16;
                int gl = kk * 4 + g;
                xf[i] = *(const short8*)&Xls[row * 64 + (gl ^ (row & 7)) * 8];
            }
#pragma unroll
            for (int j = 0; j < 4; j++) {
                int row = ww * 64 + j * 16 + c16;
                int gl = kk * 4 + g;
                wf[j] = *(const short8*)&Wls[row * 64 + (gl ^ (row & 7)) * 8];
            }
            if (z < 2) {
#pragma unroll
                for (int i = 0; i < 4; i++)
#pragma unroll
                    for (int j = 0; j < 4; j++)
                        acc[i][j] = MFMA16(xf[i], wf[j], acc[i][j]);
            } else {
#pragma unroll
                for (int i = 0; i < 4; i++)
#pragma unroll
                    for (int j = 0; j < 4; j++)
                        acc[i][j] = MFMA16(wf[i], xf[j], acc[i][j]);
            }
        }
        __syncthreads();
    }

#pragma unroll
    for (int j = 0; j < 4; j++) {
        int n = tn * 128 + wn * 64 + j * 16 + c16;
        int bi = n / 784, nn = n - bi * 784;         // z==2 only
        float bvn = (z < 2) ? bias[n] : 0.f;
#pragma unroll
        for (int i = 0; i < 4; i++) {
#pragma unroll
            for (int r4 = 0; r4 < 4; r4++) {
                int m = tm * 128 + wm * 64 + i * 16 + g * 4 + r4;
                float v = acc[i][j][r4] + ((z < 2) ? bvn : bias[m]);
                if (z == 0)      Qb[(size_t)m * 512 + n] = f2bf(v);
                else if (z == 1) Kb[(size_t)m * 512 + n] = f2bf(v);
                else {
                    int h = m >> 6, d = m & 63;
                    Vtb[(((size_t)bi * 8 + h) * 64 + d) * 784 + nn] = f2bf(v);
                }
            }
        }
    }
}

// ---------------- output projection, v9 (UNCHANGED — validated R9) ----------------
__global__ __launch_bounds__(256) void gemm_out(
    const unsigned short* __restrict__ Wto, const unsigned short* __restrict__ ctx,
    const float* __restrict__ bo, float* __restrict__ out)
{
    __shared__ unsigned short Als[128 * 64];   // 16KB Wto tile (granule-swizzled)
    __shared__ unsigned short Bls[128 * 64];   // 16KB ctx tile (granule-swizzled)
    int tid = threadIdx.x;
    int lane = tid & 63, wave = tid >> 6;
    int wm = wave & 1, wn = wave >> 1;
    int c16 = lane & 15, g = lane >> 4;

    int G = blockIdx.x;
    int i98, i4;
    if (G < 384) { i98 = (G >> 5) * 8 + (G & 7); i4 = (G >> 3) & 3; }
    else         { int r = G - 384; i98 = 96 + (r & 1); i4 = r >> 1; }
    int tm = i4, tn = i98;

    const unsigned short* Abase = Wto + (size_t)tm * 128 * 512;
    const unsigned short* Bbase = ctx + (size_t)tn * 128 * 512;

    floatx4 acc[4][4];
#pragma unroll
    for (int i = 0; i < 4; i++)
#pragma unroll
        for (int j = 0; j < 4; j++) acc[i][j] = (floatx4){0.f, 0.f, 0.f, 0.f};

    for (int kb = 0; kb < 8; ++kb) {
        int k0 = kb * 64;
#pragma unroll
        for (int rep = 0; rep < 4; ++rep) {
            int slot = rep * 256 + tid;
            int row = slot >> 3, gc = slot & 7;
            int src = gc ^ (row & 7);
            gl_lds16(Abase + (size_t)row * 512 + k0 + src * 8, &Als[slot * 8]);
            gl_lds16(Bbase + (size_t)row * 512 + k0 + src * 8, &Bls[slot * 8]);
        }
        __syncthreads();

#pragma unroll
        for (int kk = 0; kk < 2; ++kk) {
            short8 af[4], bfr[4];
#pragma unroll
            for (int i = 0; i < 4; i++) {
                int row = wm * 64 + i * 16 + c16;
                int gl = kk * 4 + g;
                af[i] = *(const short8*)&Als[row * 64 + (gl ^ (row & 7)) * 8];
            }
#pragma unroll
            for (int j = 0; j < 4; j++) {
                int row = wn * 64 + j * 16 + c16;
                int gl = kk * 4 + g;
                bfr[j] = *(const short8*)&Bls[row * 64 + (gl ^ (row & 7)) * 8];
            }
#pragma unroll
            for (int i = 0; i < 4; i++)
#pragma unroll
                for (int j = 0; j < 4; j++)
                    acc[i][j] = MFMA16(af[i], bfr[j], acc[i][j]);
        }
        __syncthreads();
    }

#pragma unroll
    for (int j = 0; j < 4; j++) {
        int n = tn * 128 + wn * 64 + j * 16 + c16;
        int bi = n / 784, q = n - bi * 784;
#pragma unroll
        for (int i = 0; i < 4; i++) {
#pragma unroll
            for (int r4 = 0; r4 < 4; r4++) {
                int m = tm * 128 + wm * 64 + i * 16 + g * 4 + r4;
                out[((size_t)bi * 512 + m) * 784 + q] = acc[i][j][r4] + bo[m];
            }
        }
    }
}

// ---------------- fused attention: EXACT round-0 v0 (FROZEN) ----------------------
// 96us. Eight restructuring attempts (occupancy split, reg prefetch, coalesce
// swap, LDS DMA, K-split, unroll x2) all regressed — the compiler's own
// schedule of the corr gathers is the optimum reachable at source level.
// Do not touch this kernel again.
__global__ __launch_bounds__(256) void attn_kernel(
    const unsigned short* __restrict__ Qb,
    const unsigned short* __restrict__ Kb,
    const unsigned short* __restrict__ Vtb,
    const float* __restrict__ corr,
    unsigned short* __restrict__ ctx)
{
    __shared__ unsigned short Plds[2][4][2][16][68];   // [parity][wave][u][row][key(64)+pad4]
    int b = blockIdx.x, qt = blockIdx.y, hh = blockIdx.z;
    int tid = threadIdx.x;
    int lane = tid & 63, w = tid >> 6;
    int h = hh * 4 + w;
    int c16 = lane & 15, g = lane >> 4;
    int q0 = qt * 32;

    short8 aq[2][2];
#pragma unroll
    for (int u = 0; u < 2; ++u) {
        int row = q0 + u * 16 + c16; row = row < 784 ? row : 783;
        const unsigned short* qp = Qb + (size_t)(b * 784 + row) * 512 + h * 64 + g * 8;
        aq[u][0] = *(const short8*)qp;
        aq[u][1] = *(const short8*)(qp + 32);
    }

    floatx4 o[2][4];
    float l[2][4];
#pragma unroll
    for (int u = 0; u < 2; ++u)
#pragma unroll
        for (int nt = 0; nt < 4; nt++) { o[u][nt] = (floatx4){0.f, 0.f, 0.f, 0.f}; l[u][nt] = 0.f; }

    const float* corrb = corr + (size_t)b * 784 * 784;
    int crow[2][4];
#pragma unroll
    for (int u = 0; u < 2; ++u)
#pragma unroll
        for (int r = 0; r < 4; ++r) {
            int rr = q0 + u * 16 + g * 4 + r; rr = rr < 784 ? rr : 783;
            crow[u][r] = rr * 784;
        }

    const unsigned short* Vh = Vtb + ((size_t)(b * 8 + h)) * 64 * 784;
    const unsigned short* Kh = Kb + (size_t)b * 784 * 512 + h * 64;

    for (int it = 0; it < 13; ++it) {
        int k0 = it * 64;
        // QK^T: s[u][t] over 64 keys
        floatx4 s[2][4];
#pragma unroll
        for (int t = 0; t < 4; ++t) {
            int key = k0 + t * 16 + c16; key = key < 784 ? key : 783;
            const unsigned short* kp = Kh + (size_t)key * 512 + g * 8;
            short8 k0f = *(const short8*)kp;
            short8 k1f = *(const short8*)(kp + 32);
#pragma unroll
            for (int u = 0; u < 2; ++u) {
                floatx4 zz = (floatx4){0.f, 0.f, 0.f, 0.f};
                zz = MFMA16(aq[u][0], k0f, zz);
                zz = MFMA16(aq[u][1], k1f, zz);
                s[u][t] = zz;
            }
        }
        // p = exp(s/8 + corr)  (no max: logits bounded by ~6)
        unsigned short* pbase = &Plds[it & 1][w][0][0][0];
#pragma unroll
        for (int u = 0; u < 2; ++u)
#pragma unroll
            for (int t = 0; t < 4; ++t) {
                int key = k0 + t * 16 + c16;
                bool valid = key < 784;
                int kc = valid ? key : 783;
#pragma unroll
                for (int r = 0; r < 4; ++r) {
                    float cv = corrb[crow[u][r] + kc];
                    float sv = fmaf(s[u][t][r], 0.125f, cv);
                    float pv = valid ? __expf(sv) : 0.f;
                    l[u][r] += pv;
                    pbase[(u * 16 + g * 4 + r) * 68 + t * 16 + c16] = f2bf(pv);
                }
            }
        // P·V
#pragma unroll
        for (int u = 0; u < 2; ++u) {
            const unsigned short* pr = &Plds[it & 1][w][u][c16][0];
            short8 pa0 = lds_read8(pr + g * 8);
            short8 pa1 = lds_read8(pr + 32 + g * 8);
#pragma unroll
            for (int nt = 0; nt < 4; ++nt) {
                int d = nt * 16 + c16;
                const unsigned short* vp = Vh + (size_t)d * 784 + k0 + g * 8;
                short8 v0 = *(const short8*)vp;
                short8 v1 = *(const short8*)(vp + 32);
                o[u][nt] = MFMA16(pa0, v0, o[u][nt]);
                o[u][nt] = MFMA16(pa1, v1, o[u][nt]);
            }
        }
    }

    // normalize and store
#pragma unroll
    for (int u = 0; u < 2; ++u)
#pragma unroll
        for (int r = 0; r < 4; ++r) {
            float lv = l[u][r];
            lv += __shfl_xor(lv, 1);
            lv += __shfl_xor(lv, 2);
            lv += __shfl_xor(lv, 4);
            lv += __shfl_xor(lv, 8);
            l[u][r] = 1.0f / lv;
        }
#pragma unroll
    for (int u = 0; u < 2; ++u)
#pragma unroll
        for (int r = 0; r < 4; ++r) {
            int row = q0 + u * 16 + g * 4 + r;
            if (row < 784) {
#pragma unroll
                for (int nt = 0; nt < 4; ++nt)
                    ctx[(size_t)(b * 784 + row) * 512 + h * 64 + nt * 16 + c16] =
                        f2bf(o[u][nt][r] * l[u][r]);
            }
        }
}

extern "C" void kernel_launch(void* const* d_in, const int* in_sizes, int n_in,
                              void* d_out, int out_size, void* d_ws, size_t ws_size,
                              hipStream_t stream) {
    (void)in_sizes; (void)n_in; (void)out_size; (void)ws_size;
    const float* queries = (const float*)d_in[0];
    const float* keys    = (const float*)d_in[1];
    const float* values  = (const float*)d_in[2];
    const float* corr    = (const float*)d_in[3];
    const float* Wq = (const float*)d_in[4];
    const float* bq = (const float*)d_in[5];
    const float* Wk = (const float*)d_in[6];
    const float* bk = (const float*)d_in[7];
    const float* Wv = (const float*)d_in[8];
    const float* bv = (const float*)d_in[9];
    const float* Wo = (const float*)d_in[10];
    const float* bo = (const float*)d_in[11];

    // workspace: Qb, Kb, Vtb, ctx (bf16, SZX each) + Wt (4 x WSEG bf16) = 53.5 MB
    unsigned short* Qb  = (unsigned short*)d_ws;
    unsigned short* Kb  = Qb + SZX;
    unsigned short* Vtb = Kb + SZX;
    unsigned short* ctx = Vtb + SZX;
    unsigned short* Wt  = ctx + SZX;

    transpose_cvt<<<dim3(16, 16, 4), dim3(32, 8), 0, stream>>>(Wq, Wk, Wv, Wo, Wt);
    gemm_qkv<<<dim3(392, 1, 3), 256, 0, stream>>>(queries, keys, values, Wt,
                                                  bq, bk, bv, Qb, Kb, Vtb);
    attn_kernel<<<dim3(16, 25, 2), 256, 0, stream>>>(Qb, Kb, Vtb, corr, ctx);
    gemm_out<<<dim3(392), 256, 0, stream>>>(Wt + 3 * WSEG, ctx, bo, (float*)d_out);
}

// Round 13
// 315.382 us; speedup vs baseline: 1.5227x; 1.0056x over previous
//
#include <hip/hip_runtime.h>

// B=16, NQ=NK=784, D_MODEL=512, H=8, DK=DV=64
#define SZX ((size_t)12544 * 512)   // elements of one [B*784, 512] matrix
#define WSEG ((size_t)262144)       // one 512x512 weight

typedef __attribute__((ext_vector_type(8))) short short8;
typedef __attribute__((ext_vector_type(4))) short short4s;
typedef __attribute__((ext_vector_type(4))) float floatx4;

typedef const __attribute__((address_space(1))) void* gas_cvp;
typedef __attribute__((address_space(3))) void* las_vp;

__device__ __forceinline__ void gl_lds16(const void* g, void* l) {
    __builtin_amdgcn_global_load_lds((gas_cvp)g, (las_vp)l, 16, 0, 0);
}

__device__ __forceinline__ unsigned short f2bf(float f) {
    unsigned int u = __float_as_uint(f);
    u += 0x7fffu + ((u >> 16) & 1u);   // RNE
    return (unsigned short)(u >> 16);
}

__device__ __forceinline__ short8 cvt8(floatx4 a, floatx4 b) {
    short8 r;
    r[0] = (short)f2bf(a[0]); r[1] = (short)f2bf(a[1]);
    r[2] = (short)f2bf(a[2]); r[3] = (short)f2bf(a[3]);
    r[4] = (short)f2bf(b[0]); r[5] = (short)f2bf(b[1]);
    r[6] = (short)f2bf(b[2]); r[7] = (short)f2bf(b[3]);
    return r;
}

__device__ __forceinline__ short8 lds_read8(const unsigned short* p) {
    // p is 8B-aligned (not 16B) — two b64 reads
    short4s a = *(const short4s*)p;
    short4s b = *(const short4s*)(p + 4);
    return __builtin_shufflevector(a, b, 0, 1, 2, 3, 4, 5, 6, 7);
}

#define MFMA16(a, b, c) __builtin_amdgcn_mfma_f32_16x16x32_bf16(a, b, c, 0, 0, 0)

// ---------------- weight transpose + convert: Wt[o][i] = bf16(W[i][o]) ------------
__global__ void transpose_cvt(const float* __restrict__ W0, const float* __restrict__ W1,
                              const float* __restrict__ W2, const float* __restrict__ W3,
                              unsigned short* __restrict__ out) {
    __shared__ float tile[32][33];
    const float* W = blockIdx.z == 0 ? W0 : blockIdx.z == 1 ? W1 : blockIdx.z == 2 ? W2 : W3;
    unsigned short* O = out + (size_t)blockIdx.z * WSEG;
    int x = blockIdx.x * 32 + threadIdx.x;
    int y0 = blockIdx.y * 32;
    for (int k = threadIdx.y; k < 32; k += 8)
        tile[k][threadIdx.x] = W[(size_t)(y0 + k) * 512 + x];
    __syncthreads();
    int xo = blockIdx.y * 32 + threadIdx.x;
    int yo0 = blockIdx.x * 32;
    for (int k = threadIdx.y; k < 32; k += 8)
        O[(size_t)(yo0 + k) * 512 + xo] = f2bf(tile[threadIdx.x][k]);
}

// ---------------- merged QKV projection GEMM, v13: 2-phase pipeline ---------------
// R12 counters: 96us with MfmaUtil 7.9 / VALUBusy 13 / HBM 16% / occ 17 — pure
// 1-phase drain-stall (stage -> full-drain barrier -> MFMA -> barrier, 8x).
// v13 = T3 minimum 2-phase (m230/m196: counted vs 1-phase = +28-41%):
//   * double-buffered LDS (Xls/Wls x2 = 64KB -> 2 blocks/CU; R12 proved
//     occupancy is NOT the lever here, so trading it for pipelining is safe)
//   * STAGE(t+1) issued BEFORE the MFMAs of t: X reg-loads + W gl_lds get the
//     whole compute phase in flight (T14 split for the reg-staged X)
//   * ONE __syncthreads per iter (half the barriers; its vmcnt+lgkm drain is
//     the only wait, and next-tile loads have had ~400cy of MFMA cover)
// dbuf WAR safety: writes at iter t target buf[(t+1)&1], last read at iter t-1,
// whose ds_reads drained at barrier(t-1) before these writes issue.
// FP order unchanged -> bit-identical (absmax tripwire 9.536743e-07).
__global__ __launch_bounds__(256) void gemm_qkv(
    const float* __restrict__ Xq, const float* __restrict__ Xk,
    const float* __restrict__ Xv, const unsigned short* __restrict__ Wt,
    const float* __restrict__ bq, const float* __restrict__ bk, const float* __restrict__ bv,
    unsigned short* __restrict__ Qb, unsigned short* __restrict__ Kb,
    unsigned short* __restrict__ Vtb)
{
    __shared__ unsigned short Xls[2][128 * 64];   // 2x16KB bf16 X-tile (granule-swizzled)
    __shared__ unsigned short Wls[2][128 * 64];   // 2x16KB bf16 W-tile (granule-swizzled)
    int z = blockIdx.z;
    const float* X = z == 0 ? Xq : z == 1 ? Xk : Xv;
    const unsigned short* Wz = Wt + (size_t)z * WSEG;
    const float* bias = z == 0 ? bq : z == 1 ? bk : bv;

    int tid = threadIdx.x;
    int lane = tid & 63, wave = tid >> 6;
    int wm = wave & 1, wn = wave >> 1;
    int c16 = lane & 15, g = lane >> 4;

    // XCD-sibling remap: blocks sharing an X row-tile get ids congruent mod 8.
    int G = blockIdx.x;
    int i98, i4;
    if (G < 384) { i98 = (G >> 5) * 8 + (G & 7); i4 = (G >> 3) & 3; }
    else         { int r = G - 384; i98 = 96 + (r & 1); i4 = r >> 1; }

    const float* Xbase = X + (size_t)i98 * 128 * 512;
    const unsigned short* Wbase = Wz + (size_t)i4 * 128 * 512;
    int tm = (z < 2) ? i98 : i4;
    int tn = (z < 2) ? i4 : i98;
    int wx = (z < 2) ? wm : wn;
    int ww = (z < 2) ? wn : wm;

    floatx4 acc[4][4];
#pragma unroll
    for (int i = 0; i < 4; i++)
#pragma unroll
        for (int j = 0; j < 4; j++) acc[i][j] = (floatx4){0.f, 0.f, 0.f, 0.f};

    // X prefetch registers: 4 granules x 2 float4 (+32 VGPR)
    floatx4 xr[4][2];

    auto xload = [&](int kb) {     // issue global f32 loads for tile kb into xr
        int k0 = kb * 64;
#pragma unroll
        for (int rep = 0; rep < 4; ++rep) {
            int slot = rep * 256 + tid;
            int row = slot >> 3, gc = slot & 7;
            const float* src = Xbase + (size_t)row * 512 + k0 + gc * 8;
            xr[rep][0] = *(const floatx4*)src;
            xr[rep][1] = *(const floatx4*)(src + 4);
        }
    };
    auto xwrite = [&](int buf) {   // convert + swizzled ds_write into Xls[buf]
#pragma unroll
        for (int rep = 0; rep < 4; ++rep) {
            int slot = rep * 256 + tid;
            int row = slot >> 3, gc = slot & 7;
            *(short8*)&Xls[buf][row * 64 + (gc ^ (row & 7)) * 8] = cvt8(xr[rep][0], xr[rep][1]);
        }
    };
    auto wstage = [&](int buf, int kb) {   // gl_lds W tile kb into Wls[buf]
        int k0 = kb * 64;
#pragma unroll
        for (int rep = 0; rep < 4; ++rep) {
            int slot = rep * 256 + tid;
            int row = slot >> 3, gc = slot & 7;
            int src = gc ^ (row & 7);
            gl_lds16(Wbase + (size_t)row * 512 + k0 + src * 8, &Wls[buf][slot * 8]);
        }
    };

    // prologue: tile 0 into buf 0
    xload(0);
    wstage(0, 0);
    xwrite(0);
    __syncthreads();

    int cur = 0;
    for (int kb = 0; kb < 8; ++kb) {
        // phase 1: issue next tile's loads (fly under this tile's MFMAs)
        if (kb < 7) {
            xload(kb + 1);
            wstage(cur ^ 1, kb + 1);
        }
        // phase 2: compute current tile
        const unsigned short* Xc = Xls[cur];
        const unsigned short* Wc = Wls[cur];
#pragma unroll
        for (int kk = 0; kk < 2; ++kk) {
            short8 xf[4], wf[4];
#pragma unroll
            for (int i = 0; i < 4; i++) {
                int row = wx * 64 + i * 16 + c16;
                int gl = kk * 4 + g;
                xf[i] = *(const short8*)&Xc[row * 64 + (gl ^ (row & 7)) * 8];
            }
#pragma unroll
            for (int j = 0; j < 4; j++) {
                int row = ww * 64 + j * 16 + c16;
                int gl = kk * 4 + g;
                wf[j] = *(const short8*)&Wc[row * 64 + (gl ^ (row & 7)) * 8];
            }
            if (z < 2) {
#pragma unroll
                for (int i = 0; i < 4; i++)
#pragma unroll
                    for (int j = 0; j < 4; j++)
                        acc[i][j] = MFMA16(xf[i], wf[j], acc[i][j]);
            } else {
#pragma unroll
                for (int i = 0; i < 4; i++)
#pragma unroll
                    for (int j = 0; j < 4; j++)
                        acc[i][j] = MFMA16(wf[i], xf[j], acc[i][j]);
            }
        }
        // phase 3: land the prefetched X into the other buffer
        if (kb < 7) xwrite(cur ^ 1);
        __syncthreads();   // single per-iter drain (vmcnt: W DMA; lgkm: X writes)
        cur ^= 1;
    }

#pragma unroll
    for (int j = 0; j < 4; j++) {
        int n = tn * 128 + wn * 64 + j * 16 + c16;
        int bi = n / 784, nn = n - bi * 784;         // z==2 only
        float bvn = (z < 2) ? bias[n] : 0.f;
#pragma unroll
        for (int i = 0; i < 4; i++) {
#pragma unroll
            for (int r4 = 0; r4 < 4; r4++) {
                int m = tm * 128 + wm * 64 + i * 16 + g * 4 + r4;
                float v = acc[i][j][r4] + ((z < 2) ? bvn : bias[m]);
                if (z == 0)      Qb[(size_t)m * 512 + n] = f2bf(v);
                else if (z == 1) Kb[(size_t)m * 512 + n] = f2bf(v);
                else {
                    int h = m >> 6, d = m & 63;
                    Vtb[(((size_t)bi * 8 + h) * 64 + d) * 784 + nn] = f2bf(v);
                }
            }
        }
    }
}

// ---------------- output projection, v13: 2-phase pipeline (pure gl_lds) ----------
// Same T3 minimum recipe as gemm_qkv, textbook form (both operands bf16 gl_lds):
// dbuf 2x(16+16)KB = 64KB; STAGE(t+1) before MFMA(t); one __syncthreads/iter.
__global__ __launch_bounds__(256) void gemm_out(
    const unsigned short* __restrict__ Wto, const unsigned short* __restrict__ ctx,
    const float* __restrict__ bo, float* __restrict__ out)
{
    __shared__ unsigned short Als[2][128 * 64];   // 2x16KB Wto tile (granule-swizzled)
    __shared__ unsigned short Bls[2][128 * 64];   // 2x16KB ctx tile (granule-swizzled)
    int tid = threadIdx.x;
    int lane = tid & 63, wave = tid >> 6;
    int wm = wave & 1, wn = wave >> 1;
    int c16 = lane & 15, g = lane >> 4;

    int G = blockIdx.x;
    int i98, i4;
    if (G < 384) { i98 = (G >> 5) * 8 + (G & 7); i4 = (G >> 3) & 3; }
    else         { int r = G - 384; i98 = 96 + (r & 1); i4 = r >> 1; }
    int tm = i4, tn = i98;

    const unsigned short* Abase = Wto + (size_t)tm * 128 * 512;
    const unsigned short* Bbase = ctx + (size_t)tn * 128 * 512;

    floatx4 acc[4][4];
#pragma unroll
    for (int i = 0; i < 4; i++)
#pragma unroll
        for (int j = 0; j < 4; j++) acc[i][j] = (floatx4){0.f, 0.f, 0.f, 0.f};

    auto stage = [&](int buf, int kb) {
        int k0 = kb * 64;
#pragma unroll
        for (int rep = 0; rep < 4; ++rep) {
            int slot = rep * 256 + tid;
            int row = slot >> 3, gc = slot & 7;
            int src = gc ^ (row & 7);
            gl_lds16(Abase + (size_t)row * 512 + k0 + src * 8, &Als[buf][slot * 8]);
            gl_lds16(Bbase + (size_t)row * 512 + k0 + src * 8, &Bls[buf][slot * 8]);
        }
    };

    stage(0, 0);
    __syncthreads();

    int cur = 0;
    for (int kb = 0; kb < 8; ++kb) {
        if (kb < 7) stage(cur ^ 1, kb + 1);   // next tile flies under this MFMA
        const unsigned short* Ac = Als[cur];
        const unsigned short* Bc = Bls[cur];
#pragma unroll
        for (int kk = 0; kk < 2; ++kk) {
            short8 af[4], bfr[4];
#pragma unroll
            for (int i = 0; i < 4; i++) {
                int row = wm * 64 + i * 16 + c16;
                int gl = kk * 4 + g;
                af[i] = *(const short8*)&Ac[row * 64 + (gl ^ (row & 7)) * 8];
            }
#pragma unroll
            for (int j = 0; j < 4; j++) {
                int row = wn * 64 + j * 16 + c16;
                int gl = kk * 4 + g;
                bfr[j] = *(const short8*)&Bc[row * 64 + (gl ^ (row & 7)) * 8];
            }
#pragma unroll
            for (int i = 0; i < 4; i++)
#pragma unroll
                for (int j = 0; j < 4; j++)
                    acc[i][j] = MFMA16(af[i], bfr[j], acc[i][j]);
        }
        __syncthreads();   // single per-iter drain
        cur ^= 1;
    }

#pragma unroll
    for (int j = 0; j < 4; j++) {
        int n = tn * 128 + wn * 64 + j * 16 + c16;
        int bi = n / 784, q = n - bi * 784;
#pragma unroll
        for (int i = 0; i < 4; i++) {
#pragma unroll
            for (int r4 = 0; r4 < 4; r4++) {
                int m = tm * 128 + wm * 64 + i * 16 + g * 4 + r4;
                out[((size_t)bi * 512 + m) * 784 + q] = acc[i][j][r4] + bo[m];
            }
        }
    }
}

// ---------------- fused attention: EXACT round-0 v0 (FROZEN) ----------------------
// 96us. Eight restructuring attempts all regressed — the compiler's own schedule
// of the corr gathers is the optimum reachable at source level. Do not touch.
__global__ __launch_bounds__(256) void attn_kernel(
    const unsigned short* __restrict__ Qb,
    const unsigned short* __restrict__ Kb,
    const unsigned short* __restrict__ Vtb,
    const float* __restrict__ corr,
    unsigned short* __restrict__ ctx)
{
    __shared__ unsigned short Plds[2][4][2][16][68];   // [parity][wave][u][row][key(64)+pad4]
    int b = blockIdx.x, qt = blockIdx.y, hh = blockIdx.z;
    int tid = threadIdx.x;
    int lane = tid & 63, w = tid >> 6;
    int h = hh * 4 + w;
    int c16 = lane & 15, g = lane >> 4;
    int q0 = qt * 32;

    short8 aq[2][2];
#pragma unroll
    for (int u = 0; u < 2; ++u) {
        int row = q0 + u * 16 + c16; row = row < 784 ? row : 783;
        const unsigned short* qp = Qb + (size_t)(b * 784 + row) * 512 + h * 64 + g * 8;
        aq[u][0] = *(const short8*)qp;
        aq[u][1] = *(const short8*)(qp + 32);
    }

    floatx4 o[2][4];
    float l[2][4];
#pragma unroll
    for (int u = 0; u < 2; ++u)
#pragma unroll
        for (int nt = 0; nt < 4; nt++) { o[u][nt] = (floatx4){0.f, 0.f, 0.f, 0.f}; l[u][nt] = 0.f; }

    const float* corrb = corr + (size_t)b * 784 * 784;
    int crow[2][4];
#pragma unroll
    for (int u = 0; u < 2; ++u)
#pragma unroll
        for (int r = 0; r < 4; ++r) {
            int rr = q0 + u * 16 + g * 4 + r; rr = rr < 784 ? rr : 783;
            crow[u][r] = rr * 784;
        }

    const unsigned short* Vh = Vtb + ((size_t)(b * 8 + h)) * 64 * 784;
    const unsigned short* Kh = Kb + (size_t)b * 784 * 512 + h * 64;

    for (int it = 0; it < 13; ++it) {
        int k0 = it * 64;
        // QK^T: s[u][t] over 64 keys
        floatx4 s[2][4];
#pragma unroll
        for (int t = 0; t < 4; ++t) {
            int key = k0 + t * 16 + c16; key = key < 784 ? key : 783;
            const unsigned short* kp = Kh + (size_t)key * 512 + g * 8;
            short8 k0f = *(const short8*)kp;
            short8 k1f = *(const short8*)(kp + 32);
#pragma unroll
            for (int u = 0; u < 2; ++u) {
                floatx4 zz = (floatx4){0.f, 0.f, 0.f, 0.f};
                zz = MFMA16(aq[u][0], k0f, zz);
                zz = MFMA16(aq[u][1], k1f, zz);
                s[u][t] = zz;
            }
        }
        // p = exp(s/8 + corr)  (no max: logits bounded by ~6)
        unsigned short* pbase = &Plds[it & 1][w][0][0][0];
#pragma unroll
        for (int u = 0; u < 2; ++u)
#pragma unroll
            for (int t = 0; t < 4; ++t) {
                int key = k0 + t * 16 + c16;
                bool valid = key < 784;
                int kc = valid ? key : 783;
#pragma unroll
                for (int r = 0; r < 4; ++r) {
                    float cv = corrb[crow[u][r] + kc];
                    float sv = fmaf(s[u][t][r], 0.125f, cv);
                    float pv = valid ? __expf(sv) : 0.f;
                    l[u][r] += pv;
                    pbase[(u * 16 + g * 4 + r) * 68 + t * 16 + c16] = f2bf(pv);
                }
            }
        // P·V
#pragma unroll
        for (int u = 0; u < 2; ++u) {
            const unsigned short* pr = &Plds[it & 1][w][u][c16][0];
            short8 pa0 = lds_read8(pr + g * 8);
            short8 pa1 = lds_read8(pr + 32 + g * 8);
#pragma unroll
            for (int nt = 0; nt < 4; ++nt) {
                int d = nt * 16 + c16;
                const unsigned short* vp = Vh + (size_t)d * 784 + k0 + g * 8;
                short8 v0 = *(const short8*)vp;
                short8 v1 = *(const short8*)(vp + 32);
                o[u][nt] = MFMA16(pa0, v0, o[u][nt]);
                o[u][nt] = MFMA16(pa1, v1, o[u][nt]);
            }
        }
    }

    // normalize and store
#pragma unroll
    for (int u = 0; u < 2; ++u)
#pragma unroll
        for (int r = 0; r < 4; ++r) {
            float lv = l[u][r];
            lv += __shfl_xor(lv, 1);
            lv += __shfl_xor(lv, 2);
            lv += __shfl_xor(lv, 4);
            lv += __shfl_xor(lv, 8);
            l[u][r] = 1.0f / lv;
        }
#pragma unroll
    for (int u = 0; u < 2; ++u)
#pragma unroll
        for (int r = 0; r < 4; ++r) {
            int row = q0 + u * 16 + g * 4 + r;
            if (row < 784) {
#pragma unroll
                for (int nt = 0; nt < 4; ++nt)
                    ctx[(size_t)(b * 784 + row) * 512 + h * 64 + nt * 16 + c16] =
                        f2bf(o[u][nt][r] * l[u][r]);
            }
        }
}

extern "C" void kernel_launch(void* const* d_in, const int* in_sizes, int n_in,
                              void* d_out, int out_size, void* d_ws, size_t ws_size,
                              hipStream_t stream) {
    (void)in_sizes; (void)n_in; (void)out_size; (void)ws_size;
    const float* queries = (const float*)d_in[0];
    const float* keys    = (const float*)d_in[1];
    const float* values  = (const float*)d_in[2];
    const float* corr    = (const float*)d_in[3];
    const float* Wq = (const float*)d_in[4];
    const float* bq = (const float*)d_in[5];
    const float* Wk = (const float*)d_in[6];
    const float* bk = (const float*)d_in[7];
    const float* Wv = (const float*)d_in[8];
    const float* bv = (const float*)d_in[9];
    const float* Wo = (const float*)d_in[10];
    const float* bo = (const float*)d_in[11];

    // workspace: Qb, Kb, Vtb, ctx (bf16, SZX each) + Wt (4 x WSEG bf16) = 53.5 MB
    unsigned short* Qb  = (unsigned short*)d_ws;
    unsigned short* Kb  = Qb + SZX;
    unsigned short* Vtb = Kb + SZX;
    unsigned short* ctx = Vtb + SZX;
    unsigned short* Wt  = ctx + SZX;

    transpose_cvt<<<dim3(16, 16, 4), dim3(32, 8), 0, stream>>>(Wq, Wk, Wv, Wo, Wt);
    gemm_qkv<<<dim3(392, 1, 3), 256, 0, stream>>>(queries, keys, values, Wt,
                                                  bq, bk, bv, Qb, Kb, Vtb);
    attn_kernel<<<dim3(16, 25, 2), 256, 0, stream>>>(Qb, Kb, Vtb, corr, ctx);
    gemm_out<<<dim3(392), 256, 0, stream>>>(Wt + 3 * WSEG, ctx, bo, (float*)d_out);
}